// Round 12
// baseline (226.170 us; speedup 1.0000x reference)
//
#include <hip/hip_runtime.h>

#define THREADS 256
#define CHUNK 4096        // edges per binA block
#define NBUCK 391         // buckets of 128 nodes (dst>>7)
#define BCAP  8192        // per-bucket edge capacity (mean 4096, 64 sigma slack)
#define CCAP  (BCAP+2048) // csr region capacity (edges + self + per-row pad to x16)

// gemm1: h = x @ W1 unscaled. 64 rows/block; wave w -> cols w*8..w*8+7.
__global__ __launch_bounds__(256)
void k_gemm1(const float* __restrict__ x, const float* __restrict__ W,
             float* __restrict__ h, int N) {
    __shared__ float xs[64][33];   // 8.4 KB, pad 33 -> conflict-free column reads
    int tid = threadIdx.x;
    int row0 = (int)blockIdx.x * 64;
    int lane = tid & 63;   // row within block
    int wid = tid >> 6;    // col group
    float acc[8];
    #pragma unroll
    for (int q = 0; q < 8; ++q) acc[q] = 0.f;
    const float4 z4 = make_float4(0.f, 0.f, 0.f, 0.f);
    for (int kc = 0; kc < 128; kc += 32) {
        __syncthreads();
        #pragma unroll
        for (int i = 0; i < 2; ++i) {
            int f = tid * 2 + i;        // 0..511
            int r = f >> 3, c4 = f & 7;
            int gr = row0 + r;
            float4 vv = (gr < N)
                ? *reinterpret_cast<const float4*>(x + (size_t)gr * 128 + kc + c4 * 4)
                : z4;
            xs[r][c4*4+0] = vv.x; xs[r][c4*4+1] = vv.y;
            xs[r][c4*4+2] = vv.z; xs[r][c4*4+3] = vv.w;
        }
        __syncthreads();
        #pragma unroll
        for (int k = 0; k < 32; ++k) {
            float xv = xs[lane][k];
            const float4* wr = reinterpret_cast<const float4*>(W + (kc + k) * 32 + wid * 8);
            float4 w0 = wr[0];   // wave-uniform -> scalar loads
            float4 w1 = wr[1];
            acc[0] += xv * w0.x; acc[1] += xv * w0.y;
            acc[2] += xv * w0.z; acc[3] += xv * w0.w;
            acc[4] += xv * w1.x; acc[5] += xv * w1.y;
            acc[6] += xv * w1.z; acc[7] += xv * w1.w;
        }
    }
    int row = row0 + lane;
    if (row < N) {
        float4* o = reinterpret_cast<float4*>(h + (size_t)row * 32 + wid * 8);
        o[0] = make_float4(acc[0], acc[1], acc[2], acc[3]);
        o[1] = make_float4(acc[4], acc[5], acc[6], acc[7]);
    } else if (row == N) {   // dummy pad row: zeros
        float4* o = reinterpret_cast<float4*>(h + (size_t)N * 32 + wid * 8);
        o[0] = z4; o[1] = z4;
    }
}

// binA: 512 threads, 4096 edges/block. Rank -> scan -> LDS stage (bucket-sorted)
// -> contiguous run writes into bucket-owned regions.
__global__ __launch_bounds__(512)
void k_binA(const int* __restrict__ src, const int* __restrict__ dst, int E,
            int* __restrict__ cursor, unsigned int* __restrict__ binned) {
    __shared__ int cnt[512];
    __shared__ int sc[512];
    __shared__ int lbase[512];
    __shared__ int gbs[512];
    __shared__ unsigned int stage[CHUNK];
    int tid = threadIdx.x;
    cnt[tid] = 0;
    __syncthreads();
    int base = (int)blockIdx.x * CHUNK;
    unsigned int pk[8];
    int rk[8];
    unsigned int mask = 0;
    #pragma unroll
    for (int i = 0; i < 2; ++i) {
        int e = base + i * 2048 + tid * 4;
        if (e + 3 < E) {
            int4 d4 = *reinterpret_cast<const int4*>(dst + e);
            int4 s4 = *reinterpret_cast<const int4*>(src + e);
            pk[i*4+0] = ((unsigned)d4.x << 16) | (unsigned)s4.x; rk[i*4+0] = atomicAdd(&cnt[d4.x >> 7], 1);
            pk[i*4+1] = ((unsigned)d4.y << 16) | (unsigned)s4.y; rk[i*4+1] = atomicAdd(&cnt[d4.y >> 7], 1);
            pk[i*4+2] = ((unsigned)d4.z << 16) | (unsigned)s4.z; rk[i*4+2] = atomicAdd(&cnt[d4.z >> 7], 1);
            pk[i*4+3] = ((unsigned)d4.w << 16) | (unsigned)s4.w; rk[i*4+3] = atomicAdd(&cnt[d4.w >> 7], 1);
            mask |= 0xFu << (i * 4);
        } else {
            for (int j = 0; j < 4; ++j) {
                int k = e + j;
                if (k < E) {
                    int d = dst[k], s = src[k];
                    pk[i*4+j] = ((unsigned)d << 16) | (unsigned)s;
                    rk[i*4+j] = atomicAdd(&cnt[d >> 7], 1);
                    mask |= 1u << (i * 4 + j);
                }
            }
        }
    }
    __syncthreads();
    int myc = cnt[tid];
    sc[tid] = myc;
    __syncthreads();
    for (int off = 1; off < 512; off <<= 1) {
        int v = (tid >= off) ? sc[tid - off] : 0;
        __syncthreads();
        sc[tid] += v;
        __syncthreads();
    }
    lbase[tid] = sc[tid] - myc;
    gbs[tid] = myc ? atomicAdd(&cursor[tid], myc) : 0;
    int nvalid = sc[511];
    __syncthreads();
    #pragma unroll
    for (int i = 0; i < 8; ++i) {
        if (mask & (1u << i)) {
            int b = pk[i] >> 23;
            stage[lbase[b] + rk[i]] = pk[i];
        }
    }
    __syncthreads();
    for (int i = tid; i < nvalid; i += 512) {
        unsigned int v = stage[i];
        int b = v >> 23;
        binned[(size_t)b * BCAP + gbs[b] + (i - lbase[b])] = v;
    }
}

// binB: one block per 128-node bucket. Single pass with rank recording.
__global__ __launch_bounds__(512)
void k_binB(const unsigned int* __restrict__ binned, const int* __restrict__ cursor,
            int* __restrict__ rowbeg, int* __restrict__ rowend, float* __restrict__ dinvg,
            unsigned short* __restrict__ csr, float* __restrict__ h, int N) {
    __shared__ int cnt[128];
    __shared__ int sc[128];
    __shared__ int excls[128];
    __shared__ float dv[128];
    int tid = threadIdx.x;
    int b = blockIdx.x;
    size_t ebase = (size_t)b * BCAP;
    int ne = cursor[b];
    if (tid < 128) cnt[tid] = 0;
    __syncthreads();
    unsigned int pk[16];
    int rk[16];
    #pragma unroll
    for (int ii = 0; ii < 16; ++ii) {
        int i = ii * 512 + tid;
        if (i < ne) {
            pk[ii] = binned[ebase + i];
            rk[ii] = atomicAdd(&cnt[(pk[ii] >> 16) & 127], 1);
        }
    }
    __syncthreads();
    int myc = 0, pcnt = 0;
    if (tid < 128) {
        myc = cnt[tid];
        pcnt = (myc + 1 + 15) & ~15;   // self + edges, padded to x16
        sc[tid] = pcnt;
    }
    __syncthreads();
    for (int off = 1; off < 128; off <<= 1) {
        int v = 0;
        if (tid < 128 && tid >= off) v = sc[tid - off];
        __syncthreads();
        if (tid < 128) sc[tid] += v;
        __syncthreads();
    }
    int cbase = b * CCAP;
    if (tid < 128) {
        int pexcl = sc[tid] - pcnt;
        excls[tid] = pexcl;
        int node = (b << 7) + tid;
        int rb = cbase + pexcl;
        float di = rsqrtf((float)(myc + 1));
        dv[tid] = di;
        if (node < N) {
            rowbeg[node] = rb;
            rowend[node] = rb + pcnt;
            dinvg[node] = di;
            csr[rb] = (unsigned short)node;   // self entry first
        }
    }
    __syncthreads();
    #pragma unroll
    for (int ii = 0; ii < 16; ++ii) {
        int i = ii * 512 + tid;
        if (i < ne) {
            int nl = (pk[ii] >> 16) & 127;
            csr[cbase + excls[nl] + 1 + rk[ii]] = (unsigned short)(pk[ii] & 0xFFFFu);
        }
    }
    __syncthreads();
    if (tid < 128) {   // fill pad slots with dummy node N (zero row)
        int pexcl = excls[tid];
        for (int p = pexcl + 1 + myc; p < pexcl + pcnt; ++p)
            csr[cbase + p] = (unsigned short)N;
    }
    __syncthreads();
    float4* h4 = reinterpret_cast<float4*>(h);
    size_t h4base = (size_t)(b << 7) * 8;
    for (int j = tid; j < 1024; j += 512) {
        int nl = j >> 3;
        if (((b << 7) + nl) < N) {
            float4 v = h4[h4base + j];
            float d = dv[nl];
            v.x *= d; v.y *= d; v.z *= d; v.w *= d;
            h4[h4base + j] = v;
        }
    }
}

// agg layer1 + bias + relu + gemm2 + dinv pre-scale. W loads AFTER gather (VGPR relief).
__global__ __launch_bounds__(THREADS)
void k_aggmm1(const float* __restrict__ hp, const int* __restrict__ rowbeg,
              const int* __restrict__ rowend, const unsigned short* __restrict__ csr,
              const float* __restrict__ dinv, const float* __restrict__ b1,
              const float* __restrict__ W2, float* __restrict__ hp2, int N) {
    int tid = threadIdx.x;
    int lane = tid & 63;
    int node = blockIdx.x * 4 + (tid >> 6);
    if (node > N) return;
    int cp = lane & 31;
    if (node == N) {   // dummy pad row of hp2: zeros
        if (lane < 8) reinterpret_cast<float4*>(hp2 + (size_t)N * 32)[lane] =
            make_float4(0.f, 0.f, 0.f, 0.f);
        return;
    }
    int j = lane >> 3, q = lane & 7;
    int beg = rowbeg[node];
    int end = rowend[node];
    float4 acc = make_float4(0.f, 0.f, 0.f, 0.f);
    float4 acc2 = make_float4(0.f, 0.f, 0.f, 0.f);
    const float4* hp4 = reinterpret_cast<const float4*>(hp);
    for (int base = beg; base < end; base += 64) {
        int idx = base + lane;
        int cv = (idx < end) ? (int)csr[idx] : 0;
        int nin = end - base; if (nin > 64) nin = 64;   // multiple of 16
        for (int c = 0; c < nin; c += 16) {
            int s0 = __shfl(cv, c + j, 64);
            int s1 = __shfl(cv, c + 8 + j, 64);
            float4 v0 = hp4[(size_t)s0 * 8 + q];
            float4 v1 = hp4[(size_t)s1 * 8 + q];
            acc.x += v0.x; acc.y += v0.y; acc.z += v0.z; acc.w += v0.w;
            acc2.x += v1.x; acc2.y += v1.y; acc2.z += v1.z; acc2.w += v1.w;
        }
    }
    acc.x += acc2.x; acc.y += acc2.y; acc.z += acc2.z; acc.w += acc2.w;
    #pragma unroll
    for (int d = 8; d < 64; d <<= 1) {
        acc.x += __shfl_xor(acc.x, d, 64);
        acc.y += __shfl_xor(acc.y, d, 64);
        acc.z += __shfl_xor(acc.z, d, 64);
        acc.w += __shfl_xor(acc.w, d, 64);
    }
    // epilogue: load W2 column + bias NOW (keeps gather-phase VGPRs low)
    float wcol[32];
    #pragma unroll
    for (int k = 0; k < 32; ++k) wcol[k] = W2[k * 32 + cp];
    float4 bv[8];
    #pragma unroll
    for (int i = 0; i < 8; ++i) bv[i] = reinterpret_cast<const float4*>(b1)[i];
    float dd = dinv[node];
    float o = 0.f;
    #pragma unroll
    for (int qq = 0; qq < 8; ++qq) {
        float t0 = __shfl(acc.x, qq, 64);
        float t1 = __shfl(acc.y, qq, 64);
        float t2 = __shfl(acc.z, qq, 64);
        float t3 = __shfl(acc.w, qq, 64);
        float y0 = fmaxf(t0 * dd + bv[qq].x, 0.f);
        float y1 = fmaxf(t1 * dd + bv[qq].y, 0.f);
        float y2 = fmaxf(t2 * dd + bv[qq].z, 0.f);
        float y3 = fmaxf(t3 * dd + bv[qq].w, 0.f);
        o += y0 * wcol[qq*4+0] + y1 * wcol[qq*4+1]
           + y2 * wcol[qq*4+2] + y3 * wcol[qq*4+3];
    }
    if (lane < 32) hp2[(size_t)node * 32 + cp] = o * dd;
}

// agg layer2 + bias + relu + head. W loads AFTER gather.
__global__ __launch_bounds__(THREADS)
void k_aggout(const float* __restrict__ hp, const int* __restrict__ rowbeg,
              const int* __restrict__ rowend, const unsigned short* __restrict__ csr,
              const float* __restrict__ dinv, const float* __restrict__ b2,
              const float* __restrict__ Wo, const float* __restrict__ bo,
              float* __restrict__ out, int N) {
    int tid = threadIdx.x;
    int lane = tid & 63;
    int node = blockIdx.x * 4 + (tid >> 6);
    if (node >= N) return;
    int j = lane >> 3, q = lane & 7;
    int beg = rowbeg[node];
    int end = rowend[node];
    float4 acc = make_float4(0.f, 0.f, 0.f, 0.f);
    float4 acc2 = make_float4(0.f, 0.f, 0.f, 0.f);
    const float4* hp4 = reinterpret_cast<const float4*>(hp);
    for (int base = beg; base < end; base += 64) {
        int idx = base + lane;
        int cv = (idx < end) ? (int)csr[idx] : 0;
        int nin = end - base; if (nin > 64) nin = 64;
        for (int c = 0; c < nin; c += 16) {
            int s0 = __shfl(cv, c + j, 64);
            int s1 = __shfl(cv, c + 8 + j, 64);
            float4 v0 = hp4[(size_t)s0 * 8 + q];
            float4 v1 = hp4[(size_t)s1 * 8 + q];
            acc.x += v0.x; acc.y += v0.y; acc.z += v0.z; acc.w += v0.w;
            acc2.x += v1.x; acc2.y += v1.y; acc2.z += v1.z; acc2.w += v1.w;
        }
    }
    acc.x += acc2.x; acc.y += acc2.y; acc.z += acc2.z; acc.w += acc2.w;
    #pragma unroll
    for (int d = 8; d < 64; d <<= 1) {
        acc.x += __shfl_xor(acc.x, d, 64);
        acc.y += __shfl_xor(acc.y, d, 64);
        acc.z += __shfl_xor(acc.z, d, 64);
        acc.w += __shfl_xor(acc.w, d, 64);
    }
    float wcol[32];
    #pragma unroll
    for (int k = 0; k < 32; ++k) wcol[k] = Wo[k * 64 + lane];
    float4 bv[8];
    #pragma unroll
    for (int i = 0; i < 8; ++i) bv[i] = reinterpret_cast<const float4*>(b2)[i];
    float dd = dinv[node];
    float o = bo[lane];
    #pragma unroll
    for (int qq = 0; qq < 8; ++qq) {
        float t0 = __shfl(acc.x, qq, 64);
        float t1 = __shfl(acc.y, qq, 64);
        float t2 = __shfl(acc.z, qq, 64);
        float t3 = __shfl(acc.w, qq, 64);
        float y0 = fmaxf(t0 * dd + bv[qq].x, 0.f);
        float y1 = fmaxf(t1 * dd + bv[qq].y, 0.f);
        float y2 = fmaxf(t2 * dd + bv[qq].z, 0.f);
        float y3 = fmaxf(t3 * dd + bv[qq].w, 0.f);
        o += y0 * wcol[qq*4+0] + y1 * wcol[qq*4+1]
           + y2 * wcol[qq*4+2] + y3 * wcol[qq*4+3];
    }
    out[(size_t)node * 64 + lane] = o;
}

extern "C" void kernel_launch(void* const* d_in, const int* in_sizes, int n_in,
                              void* d_out, int out_size, void* d_ws, size_t ws_size,
                              hipStream_t stream) {
    const float* x  = (const float*)d_in[0];
    const int*   ei = (const int*)d_in[1];
    const float* W1 = (const float*)d_in[2];
    const float* b1 = (const float*)d_in[3];
    const float* W2 = (const float*)d_in[4];
    const float* b2 = (const float*)d_in[5];
    const float* Wo = (const float*)d_in[6];
    const float* bo = (const float*)d_in[7];
    float* out = (float*)d_out;

    const int N = in_sizes[0] / 128;   // 50000
    const int E = in_sizes[1] / 2;     // 1600000
    const int* src = ei;
    const int* dst = ei + E;

    char* ws = (char*)d_ws;
    size_t off = 0;
    auto alloc = [&](size_t bytes) {
        void* p = ws + off;
        off += (bytes + 255) & ~(size_t)255;
        return p;
    };
    int*            cursor = (int*)           alloc(512 * 4);
    unsigned int*   binned = (unsigned int*)  alloc((size_t)NBUCK * BCAP * 4);
    int*            rowbeg = (int*)           alloc((size_t)N * 4);
    int*            rowend = (int*)           alloc((size_t)N * 4);
    float*          dinv   = (float*)         alloc((size_t)N * 4);
    unsigned short* csr    = (unsigned short*)alloc((size_t)NBUCK * CCAP * 2);
    float*          bufA   = (float*)         alloc((size_t)(N + 1) * 32 * 4);
    float*          bufB   = (float*)         alloc((size_t)(N + 1) * 32 * 4);

    const int nbinA  = (E + CHUNK - 1) / CHUNK;      // 391
    const int nGemm1 = (N + 64) / 64;                // 782 (covers pad row N)
    const int gAgg1  = (N + 1 + 3) / 4;              // covers node N (zero row)
    const int gAgg2  = (N + 3) / 4;

    hipMemsetAsync(cursor, 0, 512 * 4, stream);
    k_gemm1<<<nGemm1, 256, 0, stream>>>(x, W1, bufA, N);
    k_binA<<<nbinA, 512, 0, stream>>>(src, dst, E, cursor, binned);
    k_binB<<<NBUCK, 512, 0, stream>>>(binned, cursor, rowbeg, rowend, dinv,
                                      csr, bufA, N);
    k_aggmm1<<<gAgg1, THREADS, 0, stream>>>(bufA, rowbeg, rowend, csr, dinv, b1,
                                            W2, bufB, N);
    k_aggout<<<gAgg2, THREADS, 0, stream>>>(bufB, rowbeg, rowend, csr, dinv, b2,
                                            Wo, bo, out, N);
}

// Round 13
// 213.404 us; speedup vs baseline: 1.0598x; 1.0598x over previous
//
#include <hip/hip_runtime.h>

#define THREADS 256
#define CHUNK 4096        // edges per binA block
#define NBUCK 391         // buckets of 128 nodes (dst>>7)
#define BCAP  8192        // per-bucket edge capacity (mean 4096, 64 sigma slack)
#define CCAP  (BCAP+2048) // csr region capacity (edges + self + per-row pad to x16)

// gemm1: h = x @ W1 unscaled. 256 rows/block; thread = 4 rows x 8 cols.
// W1 in LDS (broadcast b128 reads); x staged TRANSPOSED so each lane reads its
// 4 rows with one conflict-free ds_read_b128. No VMEM in the K loop.
__global__ __launch_bounds__(256)
void k_gemm1(const float* __restrict__ x, const float* __restrict__ W,
             float* __restrict__ h, int N) {
    __shared__ float Wsh[128 * 32];   // 16 KB
    __shared__ float xt[32][257];     // 32.9 KB: [k in chunk][row], pitch 257
    int tid = threadIdx.x;
    int row0 = (int)blockIdx.x * 256;
    int lane = tid & 63;              // rows 4*lane .. 4*lane+3
    int cg = tid >> 6;                // cols cg*8 .. cg*8+7
    for (int j = tid; j < 1024; j += 256)
        reinterpret_cast<float4*>(Wsh)[j] = reinterpret_cast<const float4*>(W)[j];
    const float4 z4 = make_float4(0.f, 0.f, 0.f, 0.f);
    float4 acc0[4], acc1[4];
    #pragma unroll
    for (int j = 0; j < 4; ++j) { acc0[j] = z4; acc1[j] = z4; }
    for (int kc = 0; kc < 128; kc += 32) {
        __syncthreads();
        #pragma unroll
        for (int i = 0; i < 8; ++i) {
            int f = i * 256 + tid;
            int r = f >> 3, c4 = f & 7;   // row 0..255, float4-col 0..7
            int gr = row0 + r;
            float4 vv = (gr < N)
                ? *reinterpret_cast<const float4*>(x + (size_t)gr * 128 + kc + c4 * 4)
                : z4;
            xt[c4*4+0][r] = vv.x; xt[c4*4+1][r] = vv.y;
            xt[c4*4+2][r] = vv.z; xt[c4*4+3][r] = vv.w;
        }
        __syncthreads();
        #pragma unroll
        for (int k = 0; k < 32; ++k) {
            float4 xv = *reinterpret_cast<const float4*>(&xt[k][lane * 4]);
            const float4* wr = reinterpret_cast<const float4*>(Wsh + (kc + k) * 32 + cg * 8);
            float4 w0 = wr[0];   // wave-uniform LDS address -> broadcast
            float4 w1 = wr[1];
            const float* xp = reinterpret_cast<const float*>(&xv);
            #pragma unroll
            for (int j = 0; j < 4; ++j) {
                float xj = xp[j];
                acc0[j].x += xj * w0.x; acc0[j].y += xj * w0.y;
                acc0[j].z += xj * w0.z; acc0[j].w += xj * w0.w;
                acc1[j].x += xj * w1.x; acc1[j].y += xj * w1.y;
                acc1[j].z += xj * w1.z; acc1[j].w += xj * w1.w;
            }
        }
    }
    int rbase = row0 + lane * 4;
    #pragma unroll
    for (int j = 0; j < 4; ++j) {
        int row = rbase + j;
        if (row <= N) {   // row N (pad) gets zeros naturally from zero-staged xt
            float4* o = reinterpret_cast<float4*>(h + (size_t)row * 32 + cg * 8);
            o[0] = acc0[j];
            o[1] = acc1[j];
        }
    }
}

// binA: 512 threads, 4096 edges/block. Rank -> scan -> LDS stage (bucket-sorted)
// -> contiguous run writes into bucket-owned regions.
__global__ __launch_bounds__(512)
void k_binA(const int* __restrict__ src, const int* __restrict__ dst, int E,
            int* __restrict__ cursor, unsigned int* __restrict__ binned) {
    __shared__ int cnt[512];
    __shared__ int sc[512];
    __shared__ int lbase[512];
    __shared__ int gbs[512];
    __shared__ unsigned int stage[CHUNK];
    int tid = threadIdx.x;
    cnt[tid] = 0;
    __syncthreads();
    int base = (int)blockIdx.x * CHUNK;
    unsigned int pk[8];
    int rk[8];
    unsigned int mask = 0;
    #pragma unroll
    for (int i = 0; i < 2; ++i) {
        int e = base + i * 2048 + tid * 4;
        if (e + 3 < E) {
            int4 d4 = *reinterpret_cast<const int4*>(dst + e);
            int4 s4 = *reinterpret_cast<const int4*>(src + e);
            pk[i*4+0] = ((unsigned)d4.x << 16) | (unsigned)s4.x; rk[i*4+0] = atomicAdd(&cnt[d4.x >> 7], 1);
            pk[i*4+1] = ((unsigned)d4.y << 16) | (unsigned)s4.y; rk[i*4+1] = atomicAdd(&cnt[d4.y >> 7], 1);
            pk[i*4+2] = ((unsigned)d4.z << 16) | (unsigned)s4.z; rk[i*4+2] = atomicAdd(&cnt[d4.z >> 7], 1);
            pk[i*4+3] = ((unsigned)d4.w << 16) | (unsigned)s4.w; rk[i*4+3] = atomicAdd(&cnt[d4.w >> 7], 1);
            mask |= 0xFu << (i * 4);
        } else {
            for (int j = 0; j < 4; ++j) {
                int k = e + j;
                if (k < E) {
                    int d = dst[k], s = src[k];
                    pk[i*4+j] = ((unsigned)d << 16) | (unsigned)s;
                    rk[i*4+j] = atomicAdd(&cnt[d >> 7], 1);
                    mask |= 1u << (i * 4 + j);
                }
            }
        }
    }
    __syncthreads();
    int myc = cnt[tid];
    sc[tid] = myc;
    __syncthreads();
    for (int off = 1; off < 512; off <<= 1) {
        int v = (tid >= off) ? sc[tid - off] : 0;
        __syncthreads();
        sc[tid] += v;
        __syncthreads();
    }
    lbase[tid] = sc[tid] - myc;
    gbs[tid] = myc ? atomicAdd(&cursor[tid], myc) : 0;
    int nvalid = sc[511];
    __syncthreads();
    #pragma unroll
    for (int i = 0; i < 8; ++i) {
        if (mask & (1u << i)) {
            int b = pk[i] >> 23;
            stage[lbase[b] + rk[i]] = pk[i];
        }
    }
    __syncthreads();
    for (int i = tid; i < nvalid; i += 512) {
        unsigned int v = stage[i];
        int b = v >> 23;
        binned[(size_t)b * BCAP + gbs[b] + (i - lbase[b])] = v;
    }
}

// binB: one block per 128-node bucket. Single pass with rank recording.
__global__ __launch_bounds__(512)
void k_binB(const unsigned int* __restrict__ binned, const int* __restrict__ cursor,
            int* __restrict__ rowbeg, int* __restrict__ rowend, float* __restrict__ dinvg,
            unsigned short* __restrict__ csr, float* __restrict__ h, int N) {
    __shared__ int cnt[128];
    __shared__ int sc[128];
    __shared__ int excls[128];
    __shared__ float dv[128];
    int tid = threadIdx.x;
    int b = blockIdx.x;
    size_t ebase = (size_t)b * BCAP;
    int ne = cursor[b];
    if (tid < 128) cnt[tid] = 0;
    __syncthreads();
    unsigned int pk[16];
    int rk[16];
    #pragma unroll
    for (int ii = 0; ii < 16; ++ii) {
        int i = ii * 512 + tid;
        if (i < ne) {
            pk[ii] = binned[ebase + i];
            rk[ii] = atomicAdd(&cnt[(pk[ii] >> 16) & 127], 1);
        }
    }
    __syncthreads();
    int myc = 0, pcnt = 0;
    if (tid < 128) {
        myc = cnt[tid];
        pcnt = (myc + 1 + 15) & ~15;   // self + edges, padded to x16
        sc[tid] = pcnt;
    }
    __syncthreads();
    for (int off = 1; off < 128; off <<= 1) {
        int v = 0;
        if (tid < 128 && tid >= off) v = sc[tid - off];
        __syncthreads();
        if (tid < 128) sc[tid] += v;
        __syncthreads();
    }
    int cbase = b * CCAP;
    if (tid < 128) {
        int pexcl = sc[tid] - pcnt;
        excls[tid] = pexcl;
        int node = (b << 7) + tid;
        int rb = cbase + pexcl;
        float di = rsqrtf((float)(myc + 1));
        dv[tid] = di;
        if (node < N) {
            rowbeg[node] = rb;
            rowend[node] = rb + pcnt;
            dinvg[node] = di;
            csr[rb] = (unsigned short)node;   // self entry first
        }
    }
    __syncthreads();
    #pragma unroll
    for (int ii = 0; ii < 16; ++ii) {
        int i = ii * 512 + tid;
        if (i < ne) {
            int nl = (pk[ii] >> 16) & 127;
            csr[cbase + excls[nl] + 1 + rk[ii]] = (unsigned short)(pk[ii] & 0xFFFFu);
        }
    }
    __syncthreads();
    if (tid < 128) {   // fill pad slots with dummy node N (zero row)
        int pexcl = excls[tid];
        for (int p = pexcl + 1 + myc; p < pexcl + pcnt; ++p)
            csr[cbase + p] = (unsigned short)N;
    }
    __syncthreads();
    float4* h4 = reinterpret_cast<float4*>(h);
    size_t h4base = (size_t)(b << 7) * 8;
    for (int j = tid; j < 1024; j += 512) {
        int nl = j >> 3;
        if (((b << 7) + nl) < N) {
            float4 v = h4[h4base + j];
            float d = dv[nl];
            v.x *= d; v.y *= d; v.z *= d; v.w *= d;
            h4[h4base + j] = v;
        }
    }
}

// agg layer1 + bias + relu + gemm2 + dinv pre-scale. W loads AFTER gather (VGPR relief).
__global__ __launch_bounds__(THREADS)
void k_aggmm1(const float* __restrict__ hp, const int* __restrict__ rowbeg,
              const int* __restrict__ rowend, const unsigned short* __restrict__ csr,
              const float* __restrict__ dinv, const float* __restrict__ b1,
              const float* __restrict__ W2, float* __restrict__ hp2, int N) {
    int tid = threadIdx.x;
    int lane = tid & 63;
    int node = blockIdx.x * 4 + (tid >> 6);
    if (node > N) return;
    int cp = lane & 31;
    if (node == N) {   // dummy pad row of hp2: zeros
        if (lane < 8) reinterpret_cast<float4*>(hp2 + (size_t)N * 32)[lane] =
            make_float4(0.f, 0.f, 0.f, 0.f);
        return;
    }
    int j = lane >> 3, q = lane & 7;
    int beg = rowbeg[node];
    int end = rowend[node];
    float4 acc = make_float4(0.f, 0.f, 0.f, 0.f);
    float4 acc2 = make_float4(0.f, 0.f, 0.f, 0.f);
    const float4* hp4 = reinterpret_cast<const float4*>(hp);
    for (int base = beg; base < end; base += 64) {
        int idx = base + lane;
        int cv = (idx < end) ? (int)csr[idx] : 0;
        int nin = end - base; if (nin > 64) nin = 64;   // multiple of 16
        for (int c = 0; c < nin; c += 16) {
            int s0 = __shfl(cv, c + j, 64);
            int s1 = __shfl(cv, c + 8 + j, 64);
            float4 v0 = hp4[(size_t)s0 * 8 + q];
            float4 v1 = hp4[(size_t)s1 * 8 + q];
            acc.x += v0.x; acc.y += v0.y; acc.z += v0.z; acc.w += v0.w;
            acc2.x += v1.x; acc2.y += v1.y; acc2.z += v1.z; acc2.w += v1.w;
        }
    }
    acc.x += acc2.x; acc.y += acc2.y; acc.z += acc2.z; acc.w += acc2.w;
    #pragma unroll
    for (int d = 8; d < 64; d <<= 1) {
        acc.x += __shfl_xor(acc.x, d, 64);
        acc.y += __shfl_xor(acc.y, d, 64);
        acc.z += __shfl_xor(acc.z, d, 64);
        acc.w += __shfl_xor(acc.w, d, 64);
    }
    float wcol[32];
    #pragma unroll
    for (int k = 0; k < 32; ++k) wcol[k] = W2[k * 32 + cp];
    float4 bv[8];
    #pragma unroll
    for (int i = 0; i < 8; ++i) bv[i] = reinterpret_cast<const float4*>(b1)[i];
    float dd = dinv[node];
    float o = 0.f;
    #pragma unroll
    for (int qq = 0; qq < 8; ++qq) {
        float t0 = __shfl(acc.x, qq, 64);
        float t1 = __shfl(acc.y, qq, 64);
        float t2 = __shfl(acc.z, qq, 64);
        float t3 = __shfl(acc.w, qq, 64);
        float y0 = fmaxf(t0 * dd + bv[qq].x, 0.f);
        float y1 = fmaxf(t1 * dd + bv[qq].y, 0.f);
        float y2 = fmaxf(t2 * dd + bv[qq].z, 0.f);
        float y3 = fmaxf(t3 * dd + bv[qq].w, 0.f);
        o += y0 * wcol[qq*4+0] + y1 * wcol[qq*4+1]
           + y2 * wcol[qq*4+2] + y3 * wcol[qq*4+3];
    }
    if (lane < 32) hp2[(size_t)node * 32 + cp] = o * dd;
}

// agg layer2 + bias + relu + head. W loads AFTER gather.
__global__ __launch_bounds__(THREADS)
void k_aggout(const float* __restrict__ hp, const int* __restrict__ rowbeg,
              const int* __restrict__ rowend, const unsigned short* __restrict__ csr,
              const float* __restrict__ dinv, const float* __restrict__ b2,
              const float* __restrict__ Wo, const float* __restrict__ bo,
              float* __restrict__ out, int N) {
    int tid = threadIdx.x;
    int lane = tid & 63;
    int node = blockIdx.x * 4 + (tid >> 6);
    if (node >= N) return;
    int j = lane >> 3, q = lane & 7;
    int beg = rowbeg[node];
    int end = rowend[node];
    float4 acc = make_float4(0.f, 0.f, 0.f, 0.f);
    float4 acc2 = make_float4(0.f, 0.f, 0.f, 0.f);
    const float4* hp4 = reinterpret_cast<const float4*>(hp);
    for (int base = beg; base < end; base += 64) {
        int idx = base + lane;
        int cv = (idx < end) ? (int)csr[idx] : 0;
        int nin = end - base; if (nin > 64) nin = 64;
        for (int c = 0; c < nin; c += 16) {
            int s0 = __shfl(cv, c + j, 64);
            int s1 = __shfl(cv, c + 8 + j, 64);
            float4 v0 = hp4[(size_t)s0 * 8 + q];
            float4 v1 = hp4[(size_t)s1 * 8 + q];
            acc.x += v0.x; acc.y += v0.y; acc.z += v0.z; acc.w += v0.w;
            acc2.x += v1.x; acc2.y += v1.y; acc2.z += v1.z; acc2.w += v1.w;
        }
    }
    acc.x += acc2.x; acc.y += acc2.y; acc.z += acc2.z; acc.w += acc2.w;
    #pragma unroll
    for (int d = 8; d < 64; d <<= 1) {
        acc.x += __shfl_xor(acc.x, d, 64);
        acc.y += __shfl_xor(acc.y, d, 64);
        acc.z += __shfl_xor(acc.z, d, 64);
        acc.w += __shfl_xor(acc.w, d, 64);
    }
    float wcol[32];
    #pragma unroll
    for (int k = 0; k < 32; ++k) wcol[k] = Wo[k * 64 + lane];
    float4 bv[8];
    #pragma unroll
    for (int i = 0; i < 8; ++i) bv[i] = reinterpret_cast<const float4*>(b2)[i];
    float dd = dinv[node];
    float o = bo[lane];
    #pragma unroll
    for (int qq = 0; qq < 8; ++qq) {
        float t0 = __shfl(acc.x, qq, 64);
        float t1 = __shfl(acc.y, qq, 64);
        float t2 = __shfl(acc.z, qq, 64);
        float t3 = __shfl(acc.w, qq, 64);
        float y0 = fmaxf(t0 * dd + bv[qq].x, 0.f);
        float y1 = fmaxf(t1 * dd + bv[qq].y, 0.f);
        float y2 = fmaxf(t2 * dd + bv[qq].z, 0.f);
        float y3 = fmaxf(t3 * dd + bv[qq].w, 0.f);
        o += y0 * wcol[qq*4+0] + y1 * wcol[qq*4+1]
           + y2 * wcol[qq*4+2] + y3 * wcol[qq*4+3];
    }
    out[(size_t)node * 64 + lane] = o;
}

extern "C" void kernel_launch(void* const* d_in, const int* in_sizes, int n_in,
                              void* d_out, int out_size, void* d_ws, size_t ws_size,
                              hipStream_t stream) {
    const float* x  = (const float*)d_in[0];
    const int*   ei = (const int*)d_in[1];
    const float* W1 = (const float*)d_in[2];
    const float* b1 = (const float*)d_in[3];
    const float* W2 = (const float*)d_in[4];
    const float* b2 = (const float*)d_in[5];
    const float* Wo = (const float*)d_in[6];
    const float* bo = (const float*)d_in[7];
    float* out = (float*)d_out;

    const int N = in_sizes[0] / 128;   // 50000
    const int E = in_sizes[1] / 2;     // 1600000
    const int* src = ei;
    const int* dst = ei + E;

    char* ws = (char*)d_ws;
    size_t off = 0;
    auto alloc = [&](size_t bytes) {
        void* p = ws + off;
        off += (bytes + 255) & ~(size_t)255;
        return p;
    };
    int*            cursor = (int*)           alloc(512 * 4);
    unsigned int*   binned = (unsigned int*)  alloc((size_t)NBUCK * BCAP * 4);
    int*            rowbeg = (int*)           alloc((size_t)N * 4);
    int*            rowend = (int*)           alloc((size_t)N * 4);
    float*          dinv   = (float*)         alloc((size_t)N * 4);
    unsigned short* csr    = (unsigned short*)alloc((size_t)NBUCK * CCAP * 2);
    float*          bufA   = (float*)         alloc((size_t)(N + 1) * 32 * 4);
    float*          bufB   = (float*)         alloc((size_t)(N + 1) * 32 * 4);

    const int nbinA  = (E + CHUNK - 1) / CHUNK;      // 391
    const int nGemm1 = (N + 1 + 255) / 256;          // 196 (covers pad row N)
    const int gAgg1  = (N + 1 + 3) / 4;              // covers node N (zero row)
    const int gAgg2  = (N + 3) / 4;

    hipMemsetAsync(cursor, 0, 512 * 4, stream);
    k_gemm1<<<nGemm1, 256, 0, stream>>>(x, W1, bufA, N);
    k_binA<<<nbinA, 512, 0, stream>>>(src, dst, E, cursor, binned);
    k_binB<<<NBUCK, 512, 0, stream>>>(binned, cursor, rowbeg, rowend, dinv,
                                      csr, bufA, N);
    k_aggmm1<<<gAgg1, THREADS, 0, stream>>>(bufA, rowbeg, rowend, csr, dinv, b1,
                                            W2, bufB, N);
    k_aggout<<<gAgg2, THREADS, 0, stream>>>(bufB, rowbeg, rowend, csr, dinv, b2,
                                            Wo, bo, out, N);
}